// Round 7
// baseline (634.802 us; speedup 1.0000x reference)
//
#include <hip/hip_runtime.h>
#include <math.h>

#define NCLS   80
#define NPROP  1000
#define FCDIM  1024
#define DFLAT  12544   // 256*7*7
#define MPAD   1024
#define MAXR   4.1351665567423560f
#define LDSP   40      // padded LDS row stride (ushorts): 80B -> 2-way bank alias (free)
#define NMSW   16      // 1024 bits / 64 per suppression row
#define NCAT   404     // fused head cols: reg 0..319, cls 320..400, pad 401..403
#define NPIX   89250   // 67200+16800+4200+1050 pixels across the 4 levels
#define HCH    128     // channels per half

typedef unsigned short ushort_t;
typedef unsigned long long ull_t;
using short8  = __attribute__((ext_vector_type(8))) short;
using float4v = __attribute__((ext_vector_type(4))) float;

__device__ inline ushort_t f2bf(float f) {
    unsigned int u = __float_as_uint(f);
    unsigned int r = (u + 0x7fffu + ((u >> 16) & 1u)) >> 16;
    return (ushort_t)r;
}
__device__ inline float bf2f(ushort_t u) {
    return __uint_as_float(((unsigned int)u) << 16);
}

// packed fp32x2 -> bf16x2, RNE (same rounding as f2bf on normal values).
__device__ __forceinline__ unsigned cvtpk_bf16(float lo, float hi) {
    unsigned r;
    asm("v_cvt_pk_bf16_f32 %0, %1, %2" : "=v"(r) : "v"(lo), "v"(hi));
    return r;
}

// ---------------------------------------------------------------------------
// NCHW fp32 -> NHWC bf16 transpose, one 128-channel half per launch.
// Fh[(loff + p) * 128 + c_rel]. Tiled 32x32 LDS transpose, block (32,8).
// grid (2790 p-tiles over 4 concatenated levels, 4 c-tiles).
// ---------------------------------------------------------------------------
__global__ __launch_bounds__(256) void nhwc_k(
    const float* __restrict__ f0, const float* __restrict__ f1,
    const float* __restrict__ f2, const float* __restrict__ f3,
    int half, ushort_t* __restrict__ Fh)
{
    int pt = blockIdx.x;
    const float* src; int HW, loff, p0;
    if (pt < 2100)      { src = f0; HW = 67200; loff = 0;     p0 = pt * 32; }
    else if (pt < 2625) { src = f1; HW = 16800; loff = 67200; p0 = (pt - 2100) * 32; }
    else if (pt < 2757) { src = f2; HW = 4200;  loff = 84000; p0 = (pt - 2625) * 32; }
    else                { src = f3; HW = 1050;  loff = 88200; p0 = (pt - 2757) * 32; }

    int tx = threadIdx.x, ty = threadIdx.y;
    int cbase = half * HCH + blockIdx.y * 32;      // absolute channel base
    __shared__ float tile[32][33];

    #pragma unroll
    for (int i = 0; i < 4; i++) {
        int cy = ty + i * 8;
        int p  = p0 + tx;
        tile[cy][tx] = (p < HW) ? src[(size_t)(cbase + cy) * HW + p] : 0.f;
    }
    __syncthreads();
    #pragma unroll
    for (int i = 0; i < 4; i++) {
        int py = ty + i * 8;
        int p  = p0 + py;
        if (p < HW)
            Fh[(size_t)(loff + p) * HCH + blockIdx.y * 32 + tx] = f2bf(tile[tx][py]);
    }
}

// ---------------------------------------------------------------------------
// RoI Align from NHWC bf16, one block per (RoI, channel-half).
// Phase A: 196 threads compute the 49x4 sample offsets+weights ONCE into LDS
// (identical math to the previous per-lane kernel). Phase B: thread =
// (channel c 0..127, bin-parity): 16 coalesced bf16 gathers per bin
// (lane=c -> 128B/wave), fp32 accumulate, stage [c][bin] in LDS, then
// block-copy the contiguous 6272-ushort half-row to Abf (old k-order kept,
// so fc1 is untouched).
// ---------------------------------------------------------------------------
__global__ __launch_bounds__(256) void roi_nhwc_k(
    const float* __restrict__ props, const ushort_t* __restrict__ Fh,
    int half, ushort_t* __restrict__ Abf)
{
    int r = blockIdx.x;
    int t = threadIdx.x;
    ushort_t* orow = Abf + (size_t)r * DFLAT + half * (HCH * 49);

    if (r >= NPROP) {                      // zero pad rows (this half)
        for (int i = t; i < HCH * 49; i += 256) orow[i] = 0;
        return;
    }

    __shared__ int4   offs[196];           // premultiplied pixel*128 offsets
    __shared__ float4 wgts[196];
    __shared__ ushort_t obuf[HCH * 49];

    if (t < 196) {
        const float4 p = *(const float4*)&props[(size_t)r * 4];
        float wp = p.z - p.x, hp = p.w - p.y;
        float scale = sqrtf(fmaxf(wp * hp, 1e-6f));
        int lvl = (int)floorf(log2f(scale / 56.0f + 1e-6f));
        lvl = min(max(lvl, 0), 3);

        int H, W, loff; float sc;
        switch (lvl) {
            case 0:  H = 200; W = 336; sc = 0.25f;    loff = 0;     break;
            case 1:  H = 100; W = 168; sc = 0.125f;   loff = 67200; break;
            case 2:  H = 50;  W = 84;  sc = 0.0625f;  loff = 84000; break;
            default: H = 25;  W = 42;  sc = 0.03125f; loff = 88200; break;
        }

        int b   = t >> 2;          // bin 0..48
        int sub = t & 3;
        int by = b / 7, bx = b - by * 7;
        int sy = by * 2 + (sub >> 1);
        int sx = bx * 2 + (sub & 1);

        float startx = p.x * sc - 0.5f, rangex = (p.z - p.x) * sc;
        float starty = p.y * sc - 0.5f, rangey = (p.w - p.y) * sc;
        float posx = startx + (((float)sx + 0.5f) / 14.0f) * rangex;
        float posy = starty + (((float)sy + 0.5f) / 14.0f) * rangey;

        float flx = floorf(posx), fly = floorf(posy);
        float lx = posx - flx, ly = posy - fly;
        int x0 = min(max((int)flx, 0), W - 1);
        int x1 = min(x0 + 1, W - 1);
        int y0 = min(max((int)fly, 0), H - 1);
        int y1 = min(y0 + 1, H - 1);
        bool valid = (posx >= -1.0f) && (posx <= (float)W) &&
                     (posy >= -1.0f) && (posy <= (float)H);
        float vm = valid ? 0.25f : 0.0f;   // fold sample-avg 1/4 in

        wgts[t] = make_float4((1.f - ly) * (1.f - lx) * vm,
                              (1.f - ly) * lx * vm,
                              ly * (1.f - lx) * vm,
                              ly * lx * vm);
        offs[t] = make_int4((loff + y0 * W + x0) * HCH,
                            (loff + y0 * W + x1) * HCH,
                            (loff + y1 * W + x0) * HCH,
                            (loff + y1 * W + x1) * HCH);
    }
    __syncthreads();

    int c  = t & (HCH - 1);
    int bg = t >> 7;                       // bin parity
    for (int b = bg; b < 49; b += 2) {
        float acc = 0.f;
        #pragma unroll
        for (int s = 0; s < 4; s++) {
            int4   o  = offs[b * 4 + s];
            float4 wv = wgts[b * 4 + s];
            acc += wv.x * bf2f(Fh[o.x + c]) + wv.y * bf2f(Fh[o.y + c])
                 + wv.z * bf2f(Fh[o.z + c]) + wv.w * bf2f(Fh[o.w + c]);
        }
        obuf[c * 49 + b] = f2bf(acc);
    }
    __syncthreads();

    for (int i = t; i < HCH * 49; i += 256)
        orow[i] = obuf[i];
}

// ---------------------------------------------------------------------------
// Split-K bf16 MFMA GEMM: P[z] = A(MPADxK chunk) * W(NxK chunk)^T.
// Double-buffered LDS, one barrier per K-step, prefetch-before-compute,
// XCD-aware n-tile remap (bijective; gridDim.x==8).
// ---------------------------------------------------------------------------
__global__ __launch_bounds__(256) void gemm_sk_k(
    const ushort_t* __restrict__ A, const float* __restrict__ Wf,
    float* __restrict__ P, int N, int K, int KC)
{
    __shared__ ushort_t As[2][128 * LDSP];
    __shared__ ushort_t Bs[2][128 * LDSP];

    int tid = threadIdx.x;
    int w = tid >> 6, l = tid & 63;
    int wm = (w >> 1) * 64, wn = (w & 1) * 64;

    int bid = (int)blockIdx.x + (int)gridDim.x * ((int)blockIdx.y + (int)gridDim.y * (int)blockIdx.z);
    int bx = bid & 7;
    int slot = bid >> 3;
    int by = slot % (int)gridDim.y;
    int bz = slot / (int)gridDim.y;

    int m0 = by * 128, n0 = bx * 128;
    int kc0 = bz * KC;

    int lrow = tid >> 2;            // 0..63
    int lko  = (tid & 3) * 8;       // 0,8,16,24

    const ushort_t* Ag = A  + (size_t)(m0 + lrow) * K + kc0 + lko;
    const float*    Wg = Wf + (size_t)(n0 + lrow) * K + kc0 + lko;
    size_t rowK64 = (size_t)64 * K;

    float4v acc[4][4];
    #pragma unroll
    for (int i = 0; i < 4; i++)
        #pragma unroll
        for (int j = 0; j < 4; j++)
            acc[i][j] = (float4v){0.f, 0.f, 0.f, 0.f};

    int rl = l & 15, q = l >> 4;

    // ---- prologue: stage tile 0 into buffer 0 ----
    {
        uint4  a0  = *(const uint4*)(Ag);
        uint4  a1  = *(const uint4*)(Ag + rowK64);
        float4 w0a = *(const float4*)(Wg);
        float4 w0b = *(const float4*)(Wg + 4);
        float4 w1a = *(const float4*)(Wg + rowK64);
        float4 w1b = *(const float4*)(Wg + rowK64 + 4);
        uint4 wv0, wv1;
        wv0.x = cvtpk_bf16(w0a.x, w0a.y); wv0.y = cvtpk_bf16(w0a.z, w0a.w);
        wv0.z = cvtpk_bf16(w0b.x, w0b.y); wv0.w = cvtpk_bf16(w0b.z, w0b.w);
        wv1.x = cvtpk_bf16(w1a.x, w1a.y); wv1.y = cvtpk_bf16(w1a.z, w1a.w);
        wv1.z = cvtpk_bf16(w1b.x, w1b.y); wv1.w = cvtpk_bf16(w1b.z, w1b.w);
        *(uint4*)&As[0][lrow * LDSP + lko]        = a0;
        *(uint4*)&As[0][(lrow + 64) * LDSP + lko] = a1;
        *(uint4*)&Bs[0][lrow * LDSP + lko]        = wv0;
        *(uint4*)&Bs[0][(lrow + 64) * LDSP + lko] = wv1;
    }
    __syncthreads();

    int cur = 0;
    for (int k0 = 0; k0 < KC; k0 += 32) {
        bool more = (k0 + 32) < KC;

        uint4 na0, na1;
        float4 nw0a, nw0b, nw1a, nw1b;
        if (more) {
            na0  = *(const uint4*)(Ag + k0 + 32);
            na1  = *(const uint4*)(Ag + rowK64 + k0 + 32);
            nw0a = *(const float4*)(Wg + k0 + 32);
            nw0b = *(const float4*)(Wg + k0 + 36);
            nw1a = *(const float4*)(Wg + rowK64 + k0 + 32);
            nw1b = *(const float4*)(Wg + rowK64 + k0 + 36);
        }

        const ushort_t* Ac = As[cur];
        const ushort_t* Bc = Bs[cur];
        short8 af[4], bfr[4];
        #pragma unroll
        for (int i = 0; i < 4; i++)
            af[i] = *(const short8*)&Ac[(wm + i * 16 + rl) * LDSP + q * 8];
        #pragma unroll
        for (int j = 0; j < 4; j++)
            bfr[j] = *(const short8*)&Bc[(wn + j * 16 + rl) * LDSP + q * 8];

        #pragma unroll
        for (int i = 0; i < 4; i++)
            #pragma unroll
            for (int j = 0; j < 4; j++)
                acc[i][j] = __builtin_amdgcn_mfma_f32_16x16x32_bf16(
                    af[i], bfr[j], acc[i][j], 0, 0, 0);

        if (more) {
            uint4 wv0, wv1;
            wv0.x = cvtpk_bf16(nw0a.x, nw0a.y); wv0.y = cvtpk_bf16(nw0a.z, nw0a.w);
            wv0.z = cvtpk_bf16(nw0b.x, nw0b.y); wv0.w = cvtpk_bf16(nw0b.z, nw0b.w);
            wv1.x = cvtpk_bf16(nw1a.x, nw1a.y); wv1.y = cvtpk_bf16(nw1a.z, nw1a.w);
            wv1.z = cvtpk_bf16(nw1b.x, nw1b.y); wv1.w = cvtpk_bf16(nw1b.z, nw1b.w);
            ushort_t* An = As[cur ^ 1];
            ushort_t* Bn = Bs[cur ^ 1];
            *(uint4*)&An[lrow * LDSP + lko]        = na0;
            *(uint4*)&An[(lrow + 64) * LDSP + lko] = na1;
            *(uint4*)&Bn[lrow * LDSP + lko]        = wv0;
            *(uint4*)&Bn[(lrow + 64) * LDSP + lko] = wv1;
        }

        __syncthreads();
        cur ^= 1;
    }

    float* Pz = P + (size_t)bz * ((size_t)MPAD * N);
    #pragma unroll
    for (int i = 0; i < 4; i++) {
        #pragma unroll
        for (int j = 0; j < 4; j++) {
            int col = n0 + wn + j * 16 + rl;
            #pragma unroll
            for (int rr = 0; rr < 4; rr++) {
                int row = m0 + wm + i * 16 + q * 4 + rr;
                Pz[(size_t)row * N + col] = acc[i][j][rr];
            }
        }
    }
}

// ---------------------------------------------------------------------------
// Reduce SK partials + bias (+ReLU), write bf16 or fp32.
// ---------------------------------------------------------------------------
__global__ __launch_bounds__(256) void reduce_sk_k(
    const float* __restrict__ P, const float* __restrict__ bias,
    void* __restrict__ Cout, int N, int SK, int relu, int out_bf16)
{
    size_t idx = ((size_t)blockIdx.x * 256 + threadIdx.x) * 4;
    float4 s = *(const float4*)&P[idx];
    for (int z = 1; z < SK; z++) {
        float4 pv = *(const float4*)&P[(size_t)z * ((size_t)MPAD * N) + idx];
        s.x += pv.x; s.y += pv.y; s.z += pv.z; s.w += pv.w;
    }
    int n = (int)(idx % N);
    float4 b = *(const float4*)&bias[n];
    s.x += b.x; s.y += b.y; s.z += b.z; s.w += b.w;
    if (relu) {
        s.x = fmaxf(s.x, 0.f); s.y = fmaxf(s.y, 0.f);
        s.z = fmaxf(s.z, 0.f); s.w = fmaxf(s.w, 0.f);
    }
    if (out_bf16) {
        ushort4 o;
        o.x = f2bf(s.x); o.y = f2bf(s.y); o.z = f2bf(s.z); o.w = f2bf(s.w);
        *(ushort4*)&((ushort_t*)Cout)[idx] = o;
    } else {
        *(float4*)&((float*)Cout)[idx] = s;
    }
}

// ---------------------------------------------------------------------------
// Concat reg_w/cls_w (+biases) into fused head weight [NCAT][FCDIM].
// ---------------------------------------------------------------------------
__global__ __launch_bounds__(256) void concat_w_k(
    const float* __restrict__ reg_w, const float* __restrict__ cls_w,
    const float* __restrict__ reg_b, const float* __restrict__ cls_b,
    float* __restrict__ Wcat, float* __restrict__ bcat)
{
    int row = blockIdx.x;           // 0..403
    int t = threadIdx.x;            // 256 threads x float4 = 1024 floats
    float4 v = make_float4(0.f, 0.f, 0.f, 0.f);
    float bv = 0.f;
    if (row < 320) {
        v = *(const float4*)&reg_w[(size_t)row * FCDIM + t * 4];
        bv = reg_b[row];
    } else if (row < NCAT - 3) {    // 320..400
        v = *(const float4*)&cls_w[(size_t)(row - 320) * FCDIM + t * 4];
        bv = cls_b[row - 320];
    }
    *(float4*)&Wcat[(size_t)row * FCDIM + t * 4] = v;
    if (t == 0) bcat[row] = bv;
}

// ---------------------------------------------------------------------------
// fp32 GEMM (fused cls/reg head).
// ---------------------------------------------------------------------------
__global__ __launch_bounds__(256) void gemm_tn_k(
    const float* __restrict__ A, const float* __restrict__ W,
    const float* __restrict__ bias, float* __restrict__ C,
    int M, int N, int K, int relu)
{
    __shared__ float As[16][64];
    __shared__ float Bs[16][64];

    int tid = threadIdx.x;
    int tx = tid & 15;
    int ty = tid >> 4;
    int m0 = blockIdx.y * 64, n0 = blockIdx.x * 64;

    int lr = tid >> 2;
    int lk = (tid & 3) << 2;

    const float* Arow = A + (size_t)(m0 + lr) * K + lk;
    const float* Wrow = W + (size_t)(n0 + lr) * K + lk;
    bool mOK = (m0 + lr) < M;
    bool nOK = (n0 + lr) < N;

    float acc[4][4] = {};

    for (int k0 = 0; k0 < K; k0 += 16) {
        float4 av = mOK ? *(const float4*)(Arow + k0) : make_float4(0.f, 0.f, 0.f, 0.f);
        float4 wv = nOK ? *(const float4*)(Wrow + k0) : make_float4(0.f, 0.f, 0.f, 0.f);
        As[lk + 0][lr] = av.x; As[lk + 1][lr] = av.y;
        As[lk + 2][lr] = av.z; As[lk + 3][lr] = av.w;
        Bs[lk + 0][lr] = wv.x; Bs[lk + 1][lr] = wv.y;
        Bs[lk + 2][lr] = wv.z; Bs[lk + 3][lr] = wv.w;
        __syncthreads();

        #pragma unroll
        for (int kk = 0; kk < 16; kk++) {
            float4 a = *(const float4*)&As[kk][ty << 2];
            float4 b = *(const float4*)&Bs[kk][tx << 2];
            acc[0][0] += a.x * b.x; acc[0][1] += a.x * b.y;
            acc[0][2] += a.x * b.z; acc[0][3] += a.x * b.w;
            acc[1][0] += a.y * b.x; acc[1][1] += a.y * b.y;
            acc[1][2] += a.y * b.z; acc[1][3] += a.y * b.w;
            acc[2][0] += a.z * b.x; acc[2][1] += a.z * b.y;
            acc[2][2] += a.z * b.z; acc[2][3] += a.z * b.w;
            acc[3][0] += a.w * b.x; acc[3][1] += a.w * b.y;
            acc[3][2] += a.w * b.z; acc[3][3] += a.w * b.w;
        }
        __syncthreads();
    }

    #pragma unroll
    for (int i = 0; i < 4; i++) {
        int m = m0 + (ty << 2) + i;
        if (m >= M) continue;
        #pragma unroll
        for (int j = 0; j < 4; j++) {
            int n = n0 + (tx << 2) + j;
            if (n < N) {
                float v = acc[i][j] + bias[n];
                if (relu) v = fmaxf(v, 0.f);
                C[(size_t)m * N + n] = v;
            }
        }
    }
}

// ---------------------------------------------------------------------------
// Softmax over 81 classes + delta2bbox. One block per RoI.
// ---------------------------------------------------------------------------
__global__ __launch_bounds__(128) void head_post_k(
    const float* __restrict__ hr_s, const float* __restrict__ props,
    float* __restrict__ probsT, float* __restrict__ boxesT)
{
    int r = blockIdx.x, t = threadIdx.x;
    __shared__ float red[128];

    float x = (t < 81) ? hr_s[(size_t)r * NCAT + 320 + t] : -1e30f;
    red[t] = x; __syncthreads();
    for (int s = 64; s > 0; s >>= 1) {
        if (t < s) red[t] = fmaxf(red[t], red[t + s]);
        __syncthreads();
    }
    float mx = red[0];
    __syncthreads();

    float e = (t < 81) ? expf(x - mx) : 0.f;
    red[t] = e; __syncthreads();
    for (int s = 64; s > 0; s >>= 1) {
        if (t < s) red[t] += red[t + s];
        __syncthreads();
    }
    float inv = 1.f / red[0];

    if (t < NCLS) {
        probsT[(size_t)t * NPROP + r] = e * inv;

        const float4 p = *(const float4*)&props[(size_t)r * 4];
        float4 d = *(const float4*)&hr_s[(size_t)r * NCAT + t * 4];
        float dx = d.x * 0.1f, dy = d.y * 0.1f;
        float dw = fminf(fmaxf(d.z * 0.2f, -MAXR), MAXR);
        float dh = fminf(fmaxf(d.w * 0.2f, -MAXR), MAXR);
        float px = (p.x + p.z) * 0.5f, py = (p.y + p.w) * 0.5f;
        float pw = p.z - p.x, ph = p.w - p.y;
        float gw = pw * expf(dw), gh = ph * expf(dh);
        float gx = px + pw * dx, gy = py + ph * dy;
        float4 bo = make_float4(gx - gw * 0.5f, gy - gh * 0.5f,
                                gx + gw * 0.5f, gy + gh * 0.5f);
        *(float4*)&boxesT[(size_t)(t * NPROP + r) * 4] = bo;
    }
}

// ---------------------------------------------------------------------------
// Per-class stable descending bitonic sort on (score desc, idx asc).
// ---------------------------------------------------------------------------
__global__ __launch_bounds__(512) void sort_k(
    const float* __restrict__ probsT, const float* __restrict__ boxesT,
    float* __restrict__ sortedS, float* __restrict__ sortedB)
{
    int c = blockIdx.x, t = threadIdx.x;
    __shared__ float sk[1024];
    __shared__ int   si[1024];

    for (int j = t; j < 1024; j += 512) {
        sk[j] = (j < NPROP) ? probsT[(size_t)c * NPROP + j] : -1e30f;
        si[j] = j;
    }
    __syncthreads();

    for (int size = 2; size <= 1024; size <<= 1) {
        for (int stride = size >> 1; stride > 0; stride >>= 1) {
            int i = (t << 1) - (t & (stride - 1));
            int j = i + stride;
            float ka = sk[i], kb = sk[j];
            int ia = si[i], ib = si[j];
            bool aFirst = (ka > kb) || (ka == kb && ia < ib);
            bool desc = ((i & size) == 0);
            if (desc ? !aFirst : aFirst) {
                sk[i] = kb; sk[j] = ka; si[i] = ib; si[j] = ia;
            }
            __syncthreads();
        }
    }

    for (int j = t; j < NPROP; j += 512) {
        sortedS[(size_t)c * NPROP + j] = sk[j];
        const float4 bb = *(const float4*)&boxesT[(size_t)(c * NPROP + si[j]) * 4];
        *(float4*)&sortedB[(size_t)(c * NPROP + j) * 4] = bb;
    }
}

// ---------------------------------------------------------------------------
// NMS (fused): per-class mask build + barrier-free serial scan + compaction.
// ---------------------------------------------------------------------------
__global__ __launch_bounds__(256) void nms_k(
    const float* __restrict__ sortedS, const float* __restrict__ sortedB,
    ull_t* __restrict__ masks, float* __restrict__ candS, int* __restrict__ candI)
{
    int c = blockIdx.x, t = threadIdx.x;
    __shared__ float x1s[NPROP], y1s[NPROP], x2s[NPROP], y2s[NPROP], ars[NPROP];
    __shared__ unsigned char kp[NPROP];
    __shared__ int segc[256];

    for (int j = t; j < NPROP; j += 256) {
        float4 b = *(const float4*)&sortedB[(size_t)(c * NPROP + j) * 4];
        x1s[j] = b.x; y1s[j] = b.y; x2s[j] = b.z; y2s[j] = b.w;
        ars[j] = fmaxf(b.z - b.x, 0.f) * fmaxf(b.w - b.y, 0.f);
        kp[j] = sortedS[(size_t)c * NPROP + j] > 0.05f ? 1 : 0;
    }
    __syncthreads();

    ull_t* M = masks + (size_t)c * NPROP * NMSW;
    for (int i = t; i < NPROP; i += 256) {
        if (!kp[i]) continue;
        float xi1 = x1s[i], yi1 = y1s[i], xi2 = x2s[i], yi2 = y2s[i], ai = ars[i];
        for (int w = 0; w < NMSW; w++) {
            ull_t m = 0ull;
            int j0 = w << 6;
            #pragma unroll 4
            for (int k = 0; k < 64; k++) {
                int j = j0 + k;
                if (j < NPROP) {
                    float iw = fmaxf(fminf(xi2, x2s[j]) - fmaxf(xi1, x1s[j]), 0.f);
                    float ih = fmaxf(fminf(yi2, y2s[j]) - fmaxf(yi1, y1s[j]), 0.f);
                    float inter = iw * ih;
                    float iou = inter / fmaxf(ai + ars[j] - inter, 1e-8f);
                    if (iou > 0.5f) m |= (1ull << k);
                }
            }
            M[(size_t)i * NMSW + w] = m;
        }
    }
    __syncthreads();

    if (t < 64) {
        ull_t rem = 0ull;                       // lanes 0..15: suppressed words
        for (int i = 0; i < NPROP; i++) {
            if (kp[i]) {
                ull_t w = __shfl(rem, i >> 6);
                if ((w >> (i & 63)) & 1ull) {
                    if (t == 0) kp[i] = 0;      // suppressed by earlier kept box
                } else {
                    if (t < NMSW) rem |= M[(size_t)i * NMSW + t];
                }
            }
        }
    }
    __syncthreads();

    int j0 = t * 4;
    int cnt = 0;
    #pragma unroll
    for (int k = 0; k < 4; k++) {
        int j = j0 + k;
        if (j < NPROP && kp[j]) cnt++;
    }
    segc[t] = cnt;
    __syncthreads();
    for (int off = 1; off < 256; off <<= 1) {
        int add = (t >= off) ? segc[t - off] : 0;
        __syncthreads();
        segc[t] += add;
        __syncthreads();
    }
    int pos = segc[t] - cnt;        // exclusive prefix
    #pragma unroll
    for (int k = 0; k < 4; k++) {
        int j = j0 + k;
        if (j < NPROP && kp[j]) {
            if (pos < 100) {
                candS[c * 100 + pos] = sortedS[(size_t)c * NPROP + j];
                candI[c * 100 + pos] = c * NPROP + j;
            }
            pos++;
        }
    }
    int total = segc[255];
    for (int p = total + t; p < 100; p += 256) {
        candS[c * 100 + p] = -2e30f;
        candI[c * 100 + p] = 0x7fffffff;
    }
}

// ---------------------------------------------------------------------------
// Final top-100: 80-way merge, one-wave argmax via shfl butterfly.
// ---------------------------------------------------------------------------
__global__ __launch_bounds__(128) void merge_k(
    const float* __restrict__ candS, const int* __restrict__ candI,
    const float* __restrict__ sortedB, float* __restrict__ out)
{
    int t = threadIdx.x;
    __shared__ int   head[NCLS];
    __shared__ float topv[100];
    __shared__ int   topi[100];

    if (t < NCLS) head[t] = 0;
    __syncthreads();

    for (int r = 0; r < 100; r++) {
        if (t < 64) {
            float v = -2e30f; int fi = 0x7fffffff; int cls = 0;
            {
                int h = head[t];
                if (h < 100) { v = candS[t * 100 + h]; fi = candI[t * 100 + h]; cls = t; }
            }
            int c2 = t + 64;
            if (c2 < NCLS) {
                int h = head[c2];
                if (h < 100) {
                    float v2 = candS[c2 * 100 + h]; int fi2 = candI[c2 * 100 + h];
                    if (v2 > v || (v2 == v && fi2 < fi)) { v = v2; fi = fi2; cls = c2; }
                }
            }
            #pragma unroll
            for (int s = 1; s < 64; s <<= 1) {
                float ov = __shfl_xor(v, s);
                int ofi  = __shfl_xor(fi, s);
                int ocl  = __shfl_xor(cls, s);
                if (ov > v || (ov == v && ofi < fi)) { v = ov; fi = ofi; cls = ocl; }
            }
            if (t == 0) { topv[r] = v; topi[r] = fi; head[cls]++; }
        }
        __syncthreads();
    }

    if (t < 100) {
        float v = topv[t]; int fi = topi[t];
        bool valid = v > 0.0f;
        float4 bb = make_float4(0.f, 0.f, 0.f, 0.f);
        if (valid) bb = *(const float4*)&sortedB[(size_t)fi * 4];
        out[1 + t * 4 + 0] = bb.x;
        out[1 + t * 4 + 1] = bb.y;
        out[1 + t * 4 + 2] = bb.z;
        out[1 + t * 4 + 3] = bb.w;
        out[401 + t] = valid ? v : 0.0f;
        out[501 + t] = valid ? (float)(fi / NPROP) : -1.0f;
    }
    if (t == 0) {
        int n = 0;
        for (int r = 0; r < 100; r++) n += (topv[r] > 0.0f) ? 1 : 0;
        out[0] = (float)n;
    }
}

// ---------------------------------------------------------------------------
extern "C" void kernel_launch(void* const* d_in, const int* in_sizes, int n_in,
                              void* d_out, int out_size, void* d_ws, size_t ws_size,
                              hipStream_t stream)
{
    const float* f0    = (const float*)d_in[0];
    const float* f1    = (const float*)d_in[1];
    const float* f2    = (const float*)d_in[2];
    const float* f3    = (const float*)d_in[3];
    const float* props = (const float*)d_in[4];
    const float* fc1_w = (const float*)d_in[5];
    const float* fc1_b = (const float*)d_in[6];
    const float* fc2_w = (const float*)d_in[7];
    const float* fc2_b = (const float*)d_in[8];
    const float* cls_w = (const float*)d_in[9];
    const float* cls_b = (const float*)d_in[10];
    const float* reg_w = (const float*)d_in[11];
    const float* reg_b = (const float*)d_in[12];
    float* out = (float*)d_out;

    // --- workspace carve (peak <= proven 63.3 MB) ---
    unsigned char* base = (unsigned char*)d_ws;
    ushort_t* Abf  = (ushort_t*)(base);               // 25,690,112 (dead after fc1)
    ushort_t* h1   = (ushort_t*)(base + 25690112);    //  2,097,152 bf16
    // Fh (NHWC bf16 half, 22,848,000) lives ONLY during transpose+roi and
    // occupies the (later) P1 region, which is written only at fc1:
    ushort_t* Fh   = (ushort_t*)(base + 27787264);
    float*    P1   = (float*)(base + 27787264);       // 33,554,432 (SK=8 fc1 partials; dead after reduce1)
    float*    P2   = (float*)(base + 27787264);       // 16,777,216 (SK=4 fc2 partials; dead after reduce2)
    float*    h2   = (float*)(base + 44564480);       //  4,194,304 fp32
    float*    hr_s    = (float*)(base + 48758784);    //  1,616,000 (1000 x NCAT fused heads)
    float*    probsT  = (float*)(base + 50401280);    //    320,000
    float*    boxesT  = (float*)(base + 50721280);    //  1,280,000
    float*    sortedS = (float*)(base + 52001280);    //    320,000
    float*    sortedB = (float*)(base + 52321280);    //  1,280,000
    float*    candS   = (float*)(base + 53601280);    //     32,000
    int*      candI   = (int*)(base + 53633280);      //     32,000
    float*    Wcat    = (float*)(base + 53665280);    //  1,654,784 (404x1024; written after P1 dead)
    float*    bcat    = (float*)(base + 55320064);    //      1,616
    // NMS masks reuse the dead Abf region (Abf unused after fc1 gemm):
    ull_t*    masks   = (ull_t*)(base);               // 10,240,000 (80*1000*16*8)

    // 1) RoI align via NHWC: per channel-half, transpose then gather.
    //    Abf keeps the old [r][c*49+b] k-order -> fc1 untouched.
    nhwc_k<<<dim3(2790, 4), dim3(32, 8), 0, stream>>>(f0, f1, f2, f3, 0, Fh);
    roi_nhwc_k<<<MPAD, 256, 0, stream>>>(props, Fh, 0, Abf);
    nhwc_k<<<dim3(2790, 4), dim3(32, 8), 0, stream>>>(f0, f1, f2, f3, 1, Fh);
    roi_nhwc_k<<<MPAD, 256, 0, stream>>>(props, Fh, 1, Abf);

    // 2) fc1: split-K=8 (KC=1568), W converted fp32->bf16 on the fly
    gemm_sk_k<<<dim3(FCDIM / 128, MPAD / 128, 8), 256, 0, stream>>>(
        Abf, fc1_w, P1, FCDIM, DFLAT, DFLAT / 8);
    reduce_sk_k<<<(MPAD * FCDIM / 4) / 256, 256, 0, stream>>>(
        P1, fc1_b, h1, FCDIM, 8, 1, 1);

    // 2b) concat head weights (after reduce1: P1 region dead)
    concat_w_k<<<NCAT, 256, 0, stream>>>(reg_w, cls_w, reg_b, cls_b, Wcat, bcat);

    // 3) fc2: split-K=4 (KC=256)
    gemm_sk_k<<<dim3(FCDIM / 128, MPAD / 128, 4), 256, 0, stream>>>(
        h1, fc2_w, P2, FCDIM, FCDIM, FCDIM / 4);
    reduce_sk_k<<<(MPAD * FCDIM / 4) / 256, 256, 0, stream>>>(
        P2, fc2_b, h2, FCDIM, 4, 1, 0);

    // 4) fused heads (fp32): reg cols 0..319, cls cols 320..400
    gemm_tn_k<<<dim3((NCAT + 63) / 64, (NPROP + 63) / 64), 256, 0, stream>>>(
        h2, Wcat, bcat, hr_s, NPROP, NCAT, FCDIM, 0);

    // 5) post-processing
    head_post_k<<<NPROP, 128, 0, stream>>>(hr_s, props, probsT, boxesT);
    sort_k<<<NCLS, 512, 0, stream>>>(probsT, boxesT, sortedS, sortedB);
    nms_k<<<NCLS, 256, 0, stream>>>(sortedS, sortedB, masks, candS, candI);
    merge_k<<<1, 128, 0, stream>>>(candS, candI, sortedB, out);
}

// Round 8
// 544.889 us; speedup vs baseline: 1.1650x; 1.1650x over previous
//
#include <hip/hip_runtime.h>
#include <math.h>

#define NCLS   80
#define NPROP  1000
#define FCDIM  1024
#define DFLAT  12544   // 256*7*7
#define MPAD   1024
#define MAXR   4.1351665567423560f
#define LDSP   40      // padded LDS row stride (ushorts): 80B -> 2-way bank alias (free)
#define NMSW   16      // 1024 bits / 64 per suppression row
#define NCAT   404     // fused head cols: reg 0..319, cls 320..400, pad 401..403

#define CSPLIT 8       // channel-split factor for roi_align (occupancy)
#define CG     (256 / CSPLIT)

typedef unsigned short ushort_t;
typedef unsigned long long ull_t;
using short8  = __attribute__((ext_vector_type(8))) short;
using float4v = __attribute__((ext_vector_type(4))) float;

__device__ inline ushort_t f2bf(float f) {
    unsigned int u = __float_as_uint(f);
    unsigned int r = (u + 0x7fffu + ((u >> 16) & 1u)) >> 16;
    return (ushort_t)r;
}

// packed fp32x2 -> bf16x2, RNE (same rounding as f2bf on normal values).
__device__ __forceinline__ unsigned cvtpk_bf16(float lo, float hi) {
    unsigned r;
    asm("v_cvt_pk_bf16_f32 %0, %1, %2" : "=v"(r) : "v"(lo), "v"(hi));
    return r;
}

// ---------------------------------------------------------------------------
// RoI Align: lane = sample point (49 bins x 4 subsamples = 196 lanes),
// grid (MPAD, CSPLIT). Bound: TA line-request throughput (~121us measured;
// NHWC restructure attempt was SLOWER (~190us) -- reverted in R7).
// ---------------------------------------------------------------------------
__global__ __launch_bounds__(256) void roi_align_k(
    const float* __restrict__ f0, const float* __restrict__ f1,
    const float* __restrict__ f2, const float* __restrict__ f3,
    const float* __restrict__ props, ushort_t* __restrict__ Abf)
{
    int r  = blockIdx.x;
    int cz = blockIdx.y;
    int t  = threadIdx.x;

    if (r >= NPROP) {                          // zero pad rows (this chunk)
        for (int i = t; i < CG * 49; i += 256)
            Abf[(size_t)r * DFLAT + cz * (CG * 49) + i] = 0;
        return;
    }

    const float4 p = *(const float4*)&props[(size_t)r * 4];
    float wp = p.z - p.x, hp = p.w - p.y;
    float scale = sqrtf(fmaxf(wp * hp, 1e-6f));
    int lvl = (int)floorf(log2f(scale / 56.0f + 1e-6f));
    lvl = min(max(lvl, 0), 3);

    const float* f; int H, W; float sc;
    switch (lvl) {
        case 0:  f = f0; H = 200; W = 336; sc = 0.25f;    break;
        case 1:  f = f1; H = 100; W = 168; sc = 0.125f;   break;
        case 2:  f = f2; H = 50;  W = 84;  sc = 0.0625f;  break;
        default: f = f3; H = 25;  W = 42;  sc = 0.03125f; break;
    }

    if (t >= 196) return;

    int b   = t >> 2;          // bin 0..48
    int sub = t & 3;
    int by = b / 7, bx = b - by * 7;
    int sy = by * 2 + (sub >> 1);
    int sx = bx * 2 + (sub & 1);

    float startx = p.x * sc - 0.5f, rangex = (p.z - p.x) * sc;
    float starty = p.y * sc - 0.5f, rangey = (p.w - p.y) * sc;
    float posx = startx + (((float)sx + 0.5f) / 14.0f) * rangex;
    float posy = starty + (((float)sy + 0.5f) / 14.0f) * rangey;

    float flx = floorf(posx), fly = floorf(posy);
    float lx = posx - flx, ly = posy - fly;
    int x0 = min(max((int)flx, 0), W - 1);
    int y0 = min(max((int)fly, 0), H - 1);
    int y1 = min(y0 + 1, H - 1);
    bool valid = (posx >= -1.0f) && (posx <= (float)W) &&
                 (posy >= -1.0f) && (posy <= (float)H);
    float vm = valid ? 0.25f : 0.0f;           // fold sample-avg 1/4 in

    float w00 = (1.f - ly) * (1.f - lx) * vm;
    float w01 = (1.f - ly) * lx * vm;
    float w10 = ly * (1.f - lx) * vm;
    float w11 = ly * lx * vm;

    // map corners to float2 pair (xb, xb+1); right-edge clamp remaps weights
    int  xb = min(x0, W - 2);
    bool xr = (x0 == W - 1);                   // x0==x1==W-1 -> both on v1
    float wtA = xr ? 0.f : w00, wtB = xr ? (w00 + w01) : w01;
    float wbA = xr ? 0.f : w10, wbB = xr ? (w10 + w11) : w11;
    int ot = y0 * W + xb;
    int ob = y1 * W + xb;

    const int HW = H * W;
    ushort_t* orow = Abf + (size_t)r * DFLAT + cz * (CG * 49);
    const float* pl = f + (size_t)(cz * CG) * HW;

    #pragma unroll 8
    for (int c = 0; c < CG; c++) {
        float2 tv = *(const float2*)(pl + ot);
        float2 bv = *(const float2*)(pl + ob);
        float v = tv.x * wtA + tv.y * wtB + bv.x * wbA + bv.y * wbB;
        v += __shfl_xor(v, 1);
        v += __shfl_xor(v, 2);
        if (sub == 0)
            orow[c * 49 + b] = f2bf(v);
        pl += HW;
    }
}

// ---------------------------------------------------------------------------
// Split-K bf16 MFMA GEMM: P[z] = A(MPADxK chunk) * W(NxK chunk)^T.
// Double-buffered LDS, one barrier per K-step, prefetch-before-compute,
// XCD-aware n-tile remap (bijective; gridDim.x==8).
// ---------------------------------------------------------------------------
__global__ __launch_bounds__(256) void gemm_sk_k(
    const ushort_t* __restrict__ A, const float* __restrict__ Wf,
    float* __restrict__ P, int N, int K, int KC)
{
    __shared__ ushort_t As[2][128 * LDSP];
    __shared__ ushort_t Bs[2][128 * LDSP];

    int tid = threadIdx.x;
    int w = tid >> 6, l = tid & 63;
    int wm = (w >> 1) * 64, wn = (w & 1) * 64;

    int bid = (int)blockIdx.x + (int)gridDim.x * ((int)blockIdx.y + (int)gridDim.y * (int)blockIdx.z);
    int bx = bid & 7;
    int slot = bid >> 3;
    int by = slot % (int)gridDim.y;
    int bz = slot / (int)gridDim.y;

    int m0 = by * 128, n0 = bx * 128;
    int kc0 = bz * KC;

    int lrow = tid >> 2;            // 0..63
    int lko  = (tid & 3) * 8;       // 0,8,16,24

    const ushort_t* Ag = A  + (size_t)(m0 + lrow) * K + kc0 + lko;
    const float*    Wg = Wf + (size_t)(n0 + lrow) * K + kc0 + lko;
    size_t rowK64 = (size_t)64 * K;

    float4v acc[4][4];
    #pragma unroll
    for (int i = 0; i < 4; i++)
        #pragma unroll
        for (int j = 0; j < 4; j++)
            acc[i][j] = (float4v){0.f, 0.f, 0.f, 0.f};

    int rl = l & 15, q = l >> 4;

    // ---- prologue: stage tile 0 into buffer 0 ----
    {
        uint4  a0  = *(const uint4*)(Ag);
        uint4  a1  = *(const uint4*)(Ag + rowK64);
        float4 w0a = *(const float4*)(Wg);
        float4 w0b = *(const float4*)(Wg + 4);
        float4 w1a = *(const float4*)(Wg + rowK64);
        float4 w1b = *(const float4*)(Wg + rowK64 + 4);
        uint4 wv0, wv1;
        wv0.x = cvtpk_bf16(w0a.x, w0a.y); wv0.y = cvtpk_bf16(w0a.z, w0a.w);
        wv0.z = cvtpk_bf16(w0b.x, w0b.y); wv0.w = cvtpk_bf16(w0b.z, w0b.w);
        wv1.x = cvtpk_bf16(w1a.x, w1a.y); wv1.y = cvtpk_bf16(w1a.z, w1a.w);
        wv1.z = cvtpk_bf16(w1b.x, w1b.y); wv1.w = cvtpk_bf16(w1b.z, w1b.w);
        *(uint4*)&As[0][lrow * LDSP + lko]        = a0;
        *(uint4*)&As[0][(lrow + 64) * LDSP + lko] = a1;
        *(uint4*)&Bs[0][lrow * LDSP + lko]        = wv0;
        *(uint4*)&Bs[0][(lrow + 64) * LDSP + lko] = wv1;
    }
    __syncthreads();

    int cur = 0;
    for (int k0 = 0; k0 < KC; k0 += 32) {
        bool more = (k0 + 32) < KC;

        uint4 na0, na1;
        float4 nw0a, nw0b, nw1a, nw1b;
        if (more) {
            na0  = *(const uint4*)(Ag + k0 + 32);
            na1  = *(const uint4*)(Ag + rowK64 + k0 + 32);
            nw0a = *(const float4*)(Wg + k0 + 32);
            nw0b = *(const float4*)(Wg + k0 + 36);
            nw1a = *(const float4*)(Wg + rowK64 + k0 + 32);
            nw1b = *(const float4*)(Wg + rowK64 + k0 + 36);
        }

        const ushort_t* Ac = As[cur];
        const ushort_t* Bc = Bs[cur];
        short8 af[4], bfr[4];
        #pragma unroll
        for (int i = 0; i < 4; i++)
            af[i] = *(const short8*)&Ac[(wm + i * 16 + rl) * LDSP + q * 8];
        #pragma unroll
        for (int j = 0; j < 4; j++)
            bfr[j] = *(const short8*)&Bc[(wn + j * 16 + rl) * LDSP + q * 8];

        #pragma unroll
        for (int i = 0; i < 4; i++)
            #pragma unroll
            for (int j = 0; j < 4; j++)
                acc[i][j] = __builtin_amdgcn_mfma_f32_16x16x32_bf16(
                    af[i], bfr[j], acc[i][j], 0, 0, 0);

        if (more) {
            uint4 wv0, wv1;
            wv0.x = cvtpk_bf16(nw0a.x, nw0a.y); wv0.y = cvtpk_bf16(nw0a.z, nw0a.w);
            wv0.z = cvtpk_bf16(nw0b.x, nw0b.y); wv0.w = cvtpk_bf16(nw0b.z, nw0b.w);
            wv1.x = cvtpk_bf16(nw1a.x, nw1a.y); wv1.y = cvtpk_bf16(nw1a.z, nw1a.w);
            wv1.z = cvtpk_bf16(nw1b.x, nw1b.y); wv1.w = cvtpk_bf16(nw1b.z, nw1b.w);
            ushort_t* An = As[cur ^ 1];
            ushort_t* Bn = Bs[cur ^ 1];
            *(uint4*)&An[lrow * LDSP + lko]        = na0;
            *(uint4*)&An[(lrow + 64) * LDSP + lko] = na1;
            *(uint4*)&Bn[lrow * LDSP + lko]        = wv0;
            *(uint4*)&Bn[(lrow + 64) * LDSP + lko] = wv1;
        }

        __syncthreads();
        cur ^= 1;
    }

    float* Pz = P + (size_t)bz * ((size_t)MPAD * N);
    #pragma unroll
    for (int i = 0; i < 4; i++) {
        #pragma unroll
        for (int j = 0; j < 4; j++) {
            int col = n0 + wn + j * 16 + rl;
            #pragma unroll
            for (int rr = 0; rr < 4; rr++) {
                int row = m0 + wm + i * 16 + q * 4 + rr;
                Pz[(size_t)row * N + col] = acc[i][j][rr];
            }
        }
    }
}

// ---------------------------------------------------------------------------
// Reduce SK partials + bias (+ReLU), write bf16 or fp32.
// ---------------------------------------------------------------------------
__global__ __launch_bounds__(256) void reduce_sk_k(
    const float* __restrict__ P, const float* __restrict__ bias,
    void* __restrict__ Cout, int N, int SK, int relu, int out_bf16)
{
    size_t idx = ((size_t)blockIdx.x * 256 + threadIdx.x) * 4;
    float4 s = *(const float4*)&P[idx];
    for (int z = 1; z < SK; z++) {
        float4 pv = *(const float4*)&P[(size_t)z * ((size_t)MPAD * N) + idx];
        s.x += pv.x; s.y += pv.y; s.z += pv.z; s.w += pv.w;
    }
    int n = (int)(idx % N);
    float4 b = *(const float4*)&bias[n];
    s.x += b.x; s.y += b.y; s.z += b.z; s.w += b.w;
    if (relu) {
        s.x = fmaxf(s.x, 0.f); s.y = fmaxf(s.y, 0.f);
        s.z = fmaxf(s.z, 0.f); s.w = fmaxf(s.w, 0.f);
    }
    if (out_bf16) {
        ushort4 o;
        o.x = f2bf(s.x); o.y = f2bf(s.y); o.z = f2bf(s.z); o.w = f2bf(s.w);
        *(ushort4*)&((ushort_t*)Cout)[idx] = o;
    } else {
        *(float4*)&((float*)Cout)[idx] = s;
    }
}

// ---------------------------------------------------------------------------
// Concat reg_w/cls_w (+biases) into fused head weight [NCAT][FCDIM].
// ---------------------------------------------------------------------------
__global__ __launch_bounds__(256) void concat_w_k(
    const float* __restrict__ reg_w, const float* __restrict__ cls_w,
    const float* __restrict__ reg_b, const float* __restrict__ cls_b,
    float* __restrict__ Wcat, float* __restrict__ bcat)
{
    int row = blockIdx.x;           // 0..403
    int t = threadIdx.x;            // 256 threads x float4 = 1024 floats
    float4 v = make_float4(0.f, 0.f, 0.f, 0.f);
    float bv = 0.f;
    if (row < 320) {
        v = *(const float4*)&reg_w[(size_t)row * FCDIM + t * 4];
        bv = reg_b[row];
    } else if (row < NCAT - 3) {    // 320..400
        v = *(const float4*)&cls_w[(size_t)(row - 320) * FCDIM + t * 4];
        bv = cls_b[row - 320];
    }
    *(float4*)&Wcat[(size_t)row * FCDIM + t * 4] = v;
    if (t == 0) bcat[row] = bv;
}

// ---------------------------------------------------------------------------
// fp32 GEMM (fused cls/reg head).
// ---------------------------------------------------------------------------
__global__ __launch_bounds__(256) void gemm_tn_k(
    const float* __restrict__ A, const float* __restrict__ W,
    const float* __restrict__ bias, float* __restrict__ C,
    int M, int N, int K, int relu)
{
    __shared__ float As[16][64];
    __shared__ float Bs[16][64];

    int tid = threadIdx.x;
    int tx = tid & 15;
    int ty = tid >> 4;
    int m0 = blockIdx.y * 64, n0 = blockIdx.x * 64;

    int lr = tid >> 2;
    int lk = (tid & 3) << 2;

    const float* Arow = A + (size_t)(m0 + lr) * K + lk;
    const float* Wrow = W + (size_t)(n0 + lr) * K + lk;
    bool mOK = (m0 + lr) < M;
    bool nOK = (n0 + lr) < N;

    float acc[4][4] = {};

    for (int k0 = 0; k0 < K; k0 += 16) {
        float4 av = mOK ? *(const float4*)(Arow + k0) : make_float4(0.f, 0.f, 0.f, 0.f);
        float4 wv = nOK ? *(const float4*)(Wrow + k0) : make_float4(0.f, 0.f, 0.f, 0.f);
        As[lk + 0][lr] = av.x; As[lk + 1][lr] = av.y;
        As[lk + 2][lr] = av.z; As[lk + 3][lr] = av.w;
        Bs[lk + 0][lr] = wv.x; Bs[lk + 1][lr] = wv.y;
        Bs[lk + 2][lr] = wv.z; Bs[lk + 3][lr] = wv.w;
        __syncthreads();

        #pragma unroll
        for (int kk = 0; kk < 16; kk++) {
            float4 a = *(const float4*)&As[kk][ty << 2];
            float4 b = *(const float4*)&Bs[kk][tx << 2];
            acc[0][0] += a.x * b.x; acc[0][1] += a.x * b.y;
            acc[0][2] += a.x * b.z; acc[0][3] += a.x * b.w;
            acc[1][0] += a.y * b.x; acc[1][1] += a.y * b.y;
            acc[1][2] += a.y * b.z; acc[1][3] += a.y * b.w;
            acc[2][0] += a.z * b.x; acc[2][1] += a.z * b.y;
            acc[2][2] += a.z * b.z; acc[2][3] += a.z * b.w;
            acc[3][0] += a.w * b.x; acc[3][1] += a.w * b.y;
            acc[3][2] += a.w * b.z; acc[3][3] += a.w * b.w;
        }
        __syncthreads();
    }

    #pragma unroll
    for (int i = 0; i < 4; i++) {
        int m = m0 + (ty << 2) + i;
        if (m >= M) continue;
        #pragma unroll
        for (int j = 0; j < 4; j++) {
            int n = n0 + (tx << 2) + j;
            if (n < N) {
                float v = acc[i][j] + bias[n];
                if (relu) v = fmaxf(v, 0.f);
                C[(size_t)m * N + n] = v;
            }
        }
    }
}

// ---------------------------------------------------------------------------
// Softmax over 81 classes + delta2bbox. One block per RoI.
// ---------------------------------------------------------------------------
__global__ __launch_bounds__(128) void head_post_k(
    const float* __restrict__ hr_s, const float* __restrict__ props,
    float* __restrict__ probsT, float* __restrict__ boxesT)
{
    int r = blockIdx.x, t = threadIdx.x;
    __shared__ float red[128];

    float x = (t < 81) ? hr_s[(size_t)r * NCAT + 320 + t] : -1e30f;
    red[t] = x; __syncthreads();
    for (int s = 64; s > 0; s >>= 1) {
        if (t < s) red[t] = fmaxf(red[t], red[t + s]);
        __syncthreads();
    }
    float mx = red[0];
    __syncthreads();

    float e = (t < 81) ? expf(x - mx) : 0.f;
    red[t] = e; __syncthreads();
    for (int s = 64; s > 0; s >>= 1) {
        if (t < s) red[t] += red[t + s];
        __syncthreads();
    }
    float inv = 1.f / red[0];

    if (t < NCLS) {
        probsT[(size_t)t * NPROP + r] = e * inv;

        const float4 p = *(const float4*)&props[(size_t)r * 4];
        float4 d = *(const float4*)&hr_s[(size_t)r * NCAT + t * 4];
        float dx = d.x * 0.1f, dy = d.y * 0.1f;
        float dw = fminf(fmaxf(d.z * 0.2f, -MAXR), MAXR);
        float dh = fminf(fmaxf(d.w * 0.2f, -MAXR), MAXR);
        float px = (p.x + p.z) * 0.5f, py = (p.y + p.w) * 0.5f;
        float pw = p.z - p.x, ph = p.w - p.y;
        float gw = pw * expf(dw), gh = ph * expf(dh);
        float gx = px + pw * dx, gy = py + ph * dy;
        float4 bo = make_float4(gx - gw * 0.5f, gy - gh * 0.5f,
                                gx + gw * 0.5f, gy + gh * 0.5f);
        *(float4*)&boxesT[(size_t)(t * NPROP + r) * 4] = bo;
    }
}

// ---------------------------------------------------------------------------
// Per-class stable descending bitonic sort on (score desc, idx asc).
// ---------------------------------------------------------------------------
__global__ __launch_bounds__(512) void sort_k(
    const float* __restrict__ probsT, const float* __restrict__ boxesT,
    float* __restrict__ sortedS, float* __restrict__ sortedB)
{
    int c = blockIdx.x, t = threadIdx.x;
    __shared__ float sk[1024];
    __shared__ int   si[1024];

    for (int j = t; j < 1024; j += 512) {
        sk[j] = (j < NPROP) ? probsT[(size_t)c * NPROP + j] : -1e30f;
        si[j] = j;
    }
    __syncthreads();

    for (int size = 2; size <= 1024; size <<= 1) {
        for (int stride = size >> 1; stride > 0; stride >>= 1) {
            int i = (t << 1) - (t & (stride - 1));
            int j = i + stride;
            float ka = sk[i], kb = sk[j];
            int ia = si[i], ib = si[j];
            bool aFirst = (ka > kb) || (ka == kb && ia < ib);
            bool desc = ((i & size) == 0);
            if (desc ? !aFirst : aFirst) {
                sk[i] = kb; sk[j] = ka; si[i] = ib; si[j] = ia;
            }
            __syncthreads();
        }
    }

    for (int j = t; j < NPROP; j += 512) {
        sortedS[(size_t)c * NPROP + j] = sk[j];
        const float4 bb = *(const float4*)&boxesT[(size_t)(c * NPROP + si[j]) * 4];
        *(float4*)&sortedB[(size_t)(c * NPROP + j) * 4] = bb;
    }
}

// ---------------------------------------------------------------------------
// NMS (fused): per-class mask build + barrier-free serial scan + compaction.
// ---------------------------------------------------------------------------
__global__ __launch_bounds__(256) void nms_k(
    const float* __restrict__ sortedS, const float* __restrict__ sortedB,
    ull_t* __restrict__ masks, float* __restrict__ candS, int* __restrict__ candI)
{
    int c = blockIdx.x, t = threadIdx.x;
    __shared__ float x1s[NPROP], y1s[NPROP], x2s[NPROP], y2s[NPROP], ars[NPROP];
    __shared__ unsigned char kp[NPROP];
    __shared__ int segc[256];

    for (int j = t; j < NPROP; j += 256) {
        float4 b = *(const float4*)&sortedB[(size_t)(c * NPROP + j) * 4];
        x1s[j] = b.x; y1s[j] = b.y; x2s[j] = b.z; y2s[j] = b.w;
        ars[j] = fmaxf(b.z - b.x, 0.f) * fmaxf(b.w - b.y, 0.f);
        kp[j] = sortedS[(size_t)c * NPROP + j] > 0.05f ? 1 : 0;
    }
    __syncthreads();

    ull_t* M = masks + (size_t)c * NPROP * NMSW;
    for (int i = t; i < NPROP; i += 256) {
        if (!kp[i]) continue;
        float xi1 = x1s[i], yi1 = y1s[i], xi2 = x2s[i], yi2 = y2s[i], ai = ars[i];
        for (int w = 0; w < NMSW; w++) {
            ull_t m = 0ull;
            int j0 = w << 6;
            #pragma unroll 4
            for (int k = 0; k < 64; k++) {
                int j = j0 + k;
                if (j < NPROP) {
                    float iw = fmaxf(fminf(xi2, x2s[j]) - fmaxf(xi1, x1s[j]), 0.f);
                    float ih = fmaxf(fminf(yi2, y2s[j]) - fmaxf(yi1, y1s[j]), 0.f);
                    float inter = iw * ih;
                    float iou = inter / fmaxf(ai + ars[j] - inter, 1e-8f);
                    if (iou > 0.5f) m |= (1ull << k);
                }
            }
            M[(size_t)i * NMSW + w] = m;
        }
    }
    __syncthreads();

    if (t < 64) {
        ull_t rem = 0ull;                       // lanes 0..15: suppressed words
        for (int i = 0; i < NPROP; i++) {
            if (kp[i]) {
                ull_t w = __shfl(rem, i >> 6);
                if ((w >> (i & 63)) & 1ull) {
                    if (t == 0) kp[i] = 0;      // suppressed by earlier kept box
                } else {
                    if (t < NMSW) rem |= M[(size_t)i * NMSW + t];
                }
            }
        }
    }
    __syncthreads();

    int j0 = t * 4;
    int cnt = 0;
    #pragma unroll
    for (int k = 0; k < 4; k++) {
        int j = j0 + k;
        if (j < NPROP && kp[j]) cnt++;
    }
    segc[t] = cnt;
    __syncthreads();
    for (int off = 1; off < 256; off <<= 1) {
        int add = (t >= off) ? segc[t - off] : 0;
        __syncthreads();
        segc[t] += add;
        __syncthreads();
    }
    int pos = segc[t] - cnt;        // exclusive prefix
    #pragma unroll
    for (int k = 0; k < 4; k++) {
        int j = j0 + k;
        if (j < NPROP && kp[j]) {
            if (pos < 100) {
                candS[c * 100 + pos] = sortedS[(size_t)c * NPROP + j];
                candI[c * 100 + pos] = c * NPROP + j;
            }
            pos++;
        }
    }
    int total = segc[255];
    for (int p = total + t; p < 100; p += 256) {
        candS[c * 100 + p] = -2e30f;
        candI[c * 100 + p] = 0x7fffffff;
    }
}

// ---------------------------------------------------------------------------
// Final top-100: 80-way merge. v3: ALL candidates staged in LDS once
// (stride-101 padding -> conflict-free), head[] in registers, the 100
// serial rounds run in wave 0 with ZERO barriers and ZERO global loads
// (kills the ~90us dependent-global-load chain measured in R7).
// Tie-break (score desc, flat idx asc) and sentinels bit-identical.
// ---------------------------------------------------------------------------
__global__ __launch_bounds__(256) void merge_k(
    const float* __restrict__ candS, const int* __restrict__ candI,
    const float* __restrict__ sortedB, float* __restrict__ out)
{
    int t = threadIdx.x;
    __shared__ float cs[NCLS * 101];
    __shared__ int   ci[NCLS * 101];
    __shared__ float topv[100];
    __shared__ int   topi[100];

    for (int i = t; i < NCLS * 100; i += 256) {
        int c = i / 100, j = i - c * 100;
        cs[c * 101 + j] = candS[i];
        ci[c * 101 + j] = candI[i];
    }
    __syncthreads();

    if (t < 64) {
        int h1 = 0, h2 = 0;
        int c2 = t + 64;                        // valid only for t < 16
        for (int r = 0; r < 100; r++) {
            float v = -2e30f; int fi = 0x7fffffff; int cls = 0;
            if (h1 < 100) { v = cs[t * 101 + h1]; fi = ci[t * 101 + h1]; cls = t; }
            if (c2 < NCLS && h2 < 100) {
                float v2 = cs[c2 * 101 + h2]; int fi2 = ci[c2 * 101 + h2];
                if (v2 > v || (v2 == v && fi2 < fi)) { v = v2; fi = fi2; cls = c2; }
            }
            #pragma unroll
            for (int s = 1; s < 64; s <<= 1) {
                float ov = __shfl_xor(v, s);
                int ofi  = __shfl_xor(fi, s);
                int ocl  = __shfl_xor(cls, s);
                if (ov > v || (ov == v && ofi < fi)) { v = ov; fi = ofi; cls = ocl; }
            }
            if (t == 0) { topv[r] = v; topi[r] = fi; }
            if (cls == t) h1++;
            else if (c2 < NCLS && cls == c2) h2++;
        }
    }
    __syncthreads();

    if (t < 100) {
        float v = topv[t]; int fi = topi[t];
        bool valid = v > 0.0f;
        float4 bb = make_float4(0.f, 0.f, 0.f, 0.f);
        if (valid) bb = *(const float4*)&sortedB[(size_t)fi * 4];
        out[1 + t * 4 + 0] = bb.x;
        out[1 + t * 4 + 1] = bb.y;
        out[1 + t * 4 + 2] = bb.z;
        out[1 + t * 4 + 3] = bb.w;
        out[401 + t] = valid ? v : 0.0f;
        out[501 + t] = valid ? (float)(fi / NPROP) : -1.0f;
    }
    if (t == 0) {
        int n = 0;
        for (int r = 0; r < 100; r++) n += (topv[r] > 0.0f) ? 1 : 0;
        out[0] = (float)n;
    }
}

// ---------------------------------------------------------------------------
extern "C" void kernel_launch(void* const* d_in, const int* in_sizes, int n_in,
                              void* d_out, int out_size, void* d_ws, size_t ws_size,
                              hipStream_t stream)
{
    const float* f0    = (const float*)d_in[0];
    const float* f1    = (const float*)d_in[1];
    const float* f2    = (const float*)d_in[2];
    const float* f3    = (const float*)d_in[3];
    const float* props = (const float*)d_in[4];
    const float* fc1_w = (const float*)d_in[5];
    const float* fc1_b = (const float*)d_in[6];
    const float* fc2_w = (const float*)d_in[7];
    const float* fc2_b = (const float*)d_in[8];
    const float* cls_w = (const float*)d_in[9];
    const float* cls_b = (const float*)d_in[10];
    const float* reg_w = (const float*)d_in[11];
    const float* reg_b = (const float*)d_in[12];
    float* out = (float*)d_out;

    // --- workspace carve (peak <= proven 63.3 MB) ---
    unsigned char* base = (unsigned char*)d_ws;
    ushort_t* Abf  = (ushort_t*)(base);               // 25,690,112 (dead after fc1)
    ushort_t* h1   = (ushort_t*)(base + 25690112);    //  2,097,152 bf16
    float*    P1   = (float*)(base + 27787264);       // 33,554,432 (SK=8 fc1 partials; dead after reduce1)
    float*    P2   = (float*)(base + 27787264);       // 16,777,216 (SK=4 fc2 partials; dead after reduce2)
    float*    h2   = (float*)(base + 44564480);       //  4,194,304 fp32
    float*    hr_s    = (float*)(base + 48758784);    //  1,616,000 (1000 x NCAT fused heads)
    float*    probsT  = (float*)(base + 50401280);    //    320,000
    float*    boxesT  = (float*)(base + 50721280);    //  1,280,000
    float*    sortedS = (float*)(base + 52001280);    //    320,000
    float*    sortedB = (float*)(base + 52321280);    //  1,280,000
    float*    candS   = (float*)(base + 53601280);    //     32,000
    int*      candI   = (int*)(base + 53633280);      //     32,000
    float*    Wcat    = (float*)(base + 53665280);    //  1,654,784 (404x1024; written after P1 dead)
    float*    bcat    = (float*)(base + 55320064);    //      1,616
    // NMS masks reuse the dead Abf region (Abf unused after fc1 gemm):
    ull_t*    masks   = (ull_t*)(base);               // 10,240,000 (80*1000*16*8)

    // 1) RoI align -> bf16 A matrix (1024 x 12544, pad rows zeroed)
    roi_align_k<<<dim3(MPAD, CSPLIT), 256, 0, stream>>>(f0, f1, f2, f3, props, Abf);

    // 2) fc1: split-K=8 (KC=1568), W converted fp32->bf16 on the fly
    gemm_sk_k<<<dim3(FCDIM / 128, MPAD / 128, 8), 256, 0, stream>>>(
        Abf, fc1_w, P1, FCDIM, DFLAT, DFLAT / 8);
    reduce_sk_k<<<(MPAD * FCDIM / 4) / 256, 256, 0, stream>>>(
        P1, fc1_b, h1, FCDIM, 8, 1, 1);

    // 2b) concat head weights (after reduce1: P1 region dead)
    concat_w_k<<<NCAT, 256, 0, stream>>>(reg_w, cls_w, reg_b, cls_b, Wcat, bcat);

    // 3) fc2: split-K=4 (KC=256)
    gemm_sk_k<<<dim3(FCDIM / 128, MPAD / 128, 4), 256, 0, stream>>>(
        h1, fc2_w, P2, FCDIM, FCDIM, FCDIM / 4);
    reduce_sk_k<<<(MPAD * FCDIM / 4) / 256, 256, 0, stream>>>(
        P2, fc2_b, h2, FCDIM, 4, 1, 0);

    // 4) fused heads (fp32): reg cols 0..319, cls cols 320..400
    gemm_tn_k<<<dim3((NCAT + 63) / 64, (NPROP + 63) / 64), 256, 0, stream>>>(
        h2, Wcat, bcat, hr_s, NPROP, NCAT, FCDIM, 0);

    // 5) post-processing
    head_post_k<<<NPROP, 128, 0, stream>>>(hr_s, props, probsT, boxesT);
    sort_k<<<NCLS, 512, 0, stream>>>(probsT, boxesT, sortedS, sortedB);
    nms_k<<<NCLS, 256, 0, stream>>>(sortedS, sortedB, masks, candS, candI);
    merge_k<<<1, 256, 0, stream>>>(candS, candI, sortedB, out);
}